// Round 11
// baseline (321.595 us; speedup 1.0000x reference)
//
#include <hip/hip_runtime.h>
#include <math.h>

#define NB 64
#define TPB 256

// 1/k! for k = 0..13 (degree-13 Taylor)
__device__ __constant__ float CF[16] = {
    1.0f,
    1.0f,
    0.5f,
    1.6666666666666666e-01f,
    4.1666666666666664e-02f,
    8.3333333333333332e-03f,
    1.3888888888888889e-03f,
    1.9841269841269841e-04f,
    2.4801587301587302e-05f,
    2.7557319223985893e-06f,
    2.7557319223985888e-07f,
    2.5052108385441720e-08f,
    2.0876756987868100e-09f,
    1.6059043836821613e-10f,
    1.1470745597729725e-11f,
    7.6471637318198164e-13f
};

typedef __attribute__((ext_vector_type(8))) short bf16x8;
typedef __attribute__((ext_vector_type(16))) float f32x16;
typedef __attribute__((ext_vector_type(4))) unsigned int u32x4;

#define MFMA32 __builtin_amdgcn_mfma_f32_32x32x16_bf16

// packed split: (x0,x1) -> hi word (bf16(x0)|bf16(x1)<<16), lo word (residuals)
__device__ __forceinline__ void split_pk(float x0, float x1, unsigned& ph, unsigned& pl) {
    unsigned h;
    asm("v_cvt_pk_bf16_f32 %0, %1, %2" : "=v"(h) : "v"(x0), "v"(x1));
    float h0 = __builtin_bit_cast(float, h << 16);
    float h1 = __builtin_bit_cast(float, h & 0xFFFF0000u);
    float r0 = x0 - h0;
    float r1 = x1 - h1;
    unsigned l;
    asm("v_cvt_pk_bf16_f32 %0, %1, %2" : "=v"(l) : "v"(r0), "v"(r1));
    ph = h; pl = l;
}

__device__ __forceinline__ float bf2f(unsigned short h) {
    unsigned u = ((unsigned)h) << 16;
    return __builtin_bit_cast(float, u);
}

// byte offset of (row, byteInRow) in a swizzled 64x64 bf16 LDS matrix (128 B rows)
__device__ __forceinline__ unsigned swzoff(int row, int byteInRow) {
    return (unsigned)(row * 128 + (byteInRow ^ ((row & 7) << 4)));
}

// A/B fragment for v_mfma_f32_32x32x16_bf16, k-step f (k in [16f,16f+16)).
// lane: row = rowbase + (lane&31), k = 16f + 8*(lane>>5) + 0..7  -> 16B read.
__device__ __forceinline__ bf16x8 ldfrag(const unsigned short* buf, int row, int f, int lh) {
    const char* p = (const char*)buf + swzoff(row, f * 32 + lh * 16);
    return __builtin_bit_cast(bf16x8, *(const u32x4*)p);
}

// acc = Ahi*Bhi + Alo*Bhi + Ahi*Blo  over K=64 (4 k-steps each)
__device__ __forceinline__ f32x16 mm3(const bf16x8* ah, const bf16x8* al,
                                      const bf16x8* bh, const bf16x8* bl) {
    f32x16 acc = {};
#pragma unroll
    for (int f = 0; f < 4; ++f) acc = MFMA32(ah[f], bh[f], acc, 0, 0, 0);
#pragma unroll
    for (int f = 0; f < 4; ++f) acc = MFMA32(al[f], bh[f], acc, 0, 0, 0);
#pragma unroll
    for (int f = 0; f < 4; ++f) acc = MFMA32(ah[f], bl[f], acc, 0, 0, 0);
    return acc;
}

// Split v[16] into hi/lo bf16 and write TRANSPOSED: value (row r_out, col c_out)
// goes to LDS[c_out][r_out]. Waves write DISJOINT (row,col) ranges, so in-place
// rewrites of the single buffer are safe once a read-drain barrier has passed.
__device__ __forceinline__ void store_cT(unsigned short* Bh, unsigned short* Bl,
                                         const float* v, int c_out, int rbase) {
#pragma unroll
    for (int g = 0; g < 4; ++g) {
        uint2 wh, wl;
        split_pk(v[g * 4 + 0], v[g * 4 + 1], wh.x, wl.x);
        split_pk(v[g * 4 + 2], v[g * 4 + 3], wh.y, wl.y);
        unsigned off = swzoff(c_out, (rbase + g * 8) * 2);
        *(uint2*)((char*)Bh + off) = wh;
        *(uint2*)((char*)Bl + off) = wl;
    }
}

// launch_bounds(256,4): (256,5) forced VGPR->48 WITH SCRATCH SPILLS (R8).
// Actual VGPR is 64 -> 8 waves/SIMD possible; LDS 16.5KB -> 8+ blocks/CU.
// Runtime occupancy = resource-min; launch_bounds does not cap it.
__global__ __launch_bounds__(TPB, 4)
void spd_expmap_mfma(const float* __restrict__ in, float* __restrict__ out)
{
    // SINGLE 16 KiB buffer (hi + lo), used in place by every stage:
    // X -> Y -> P ... with read-drain + write-visible barriers per stage.
    __shared__ __align__(16) unsigned short SB[2 * 4096];
    __shared__ float fscratch[4];
    unsigned short* Bh = SB;
    unsigned short* Bl = SB + 4096;

    const int tid  = threadIdx.x;
    const int lane = tid & 63;
    const int wv   = tid >> 6;
    const int wr   = (wv >> 1) * 32;   // wave's output row-block
    const int wc   = (wv & 1) * 32;    // wave's output col-block
    const int l31  = lane & 31;
    const int lh   = lane >> 5;
    const int c_out = wc + l31;                 // C/D: col = lane&31
    const int rbase = wr + 4 * lh;              // C/D: row = (reg&3)+8*(reg>>2)+4*(lane>>5)
    const size_t base = (size_t)blockIdx.x * (NB * NB);
    const bool diag = (wr == wc);

    // float diagonal selector
    float dsel[16];
#pragma unroll
    for (int g = 0; g < 4; ++g)
#pragma unroll
        for (int q = 0; q < 4; ++q)
            dsel[g * 4 + q] = (rbase + g * 8 + q == c_out) ? 1.0f : 0.0f;

    // ---- load A (fp32), split hi/lo, store swizzled into B ----
    {
        const int r  = tid >> 2;
        const int cb = (tid & 3) * 16;
        const float4* gp = (const float4*)(in + base) + tid * 4;
        float vv[16];
#pragma unroll
        for (int i = 0; i < 4; ++i) {
            float4 t = gp[i];
            vv[i * 4 + 0] = t.x; vv[i * 4 + 1] = t.y;
            vv[i * 4 + 2] = t.z; vv[i * 4 + 3] = t.w;
        }
        unsigned hw[8], lw[8];
#pragma unroll
        for (int i = 0; i < 8; ++i)
            split_pk(vv[2 * i], vv[2 * i + 1], hw[i], lw[i]);
        u32x4 H0 = {hw[0], hw[1], hw[2], hw[3]}, H1 = {hw[4], hw[5], hw[6], hw[7]};
        u32x4 L0 = {lw[0], lw[1], lw[2], lw[3]}, L1 = {lw[4], lw[5], lw[6], lw[7]};
        unsigned o0 = swzoff(r, cb * 2), o1 = swzoff(r, cb * 2 + 16);
        *(u32x4*)((char*)Bh + o0) = H0; *(u32x4*)((char*)Bh + o1) = H1;
        *(u32x4*)((char*)Bl + o0) = L0; *(u32x4*)((char*)Bl + o1) = L1;
    }
    __syncthreads();   // S1: X visible

    // ---- mm1: acc = X*X + per-wave Frobenius partial; x_raw read (X still live) ----
    f32x16 acc;
    {
        bf16x8 ah[4], al[4], bh[4], bl[4];
#pragma unroll
        for (int f = 0; f < 4; ++f) {
            ah[f] = ldfrag(Bh, wr + l31, f, lh);
            al[f] = ldfrag(Bl, wr + l31, f, lh);
        }
        if (diag) {
#pragma unroll
            for (int f = 0; f < 4; ++f) { bh[f] = ah[f]; bl[f] = al[f]; }
        } else {
#pragma unroll
            for (int f = 0; f < 4; ++f) {
                bh[f] = ldfrag(Bh, wc + l31, f, lh);
                bl[f] = ldfrag(Bl, wc + l31, f, lh);
            }
        }
        acc = mm3(ah, al, bh, bl);
        float fr = 0.f;
#pragma unroll
        for (int r = 0; r < 16; ++r) fr += acc[r] * acc[r];
#pragma unroll
        for (int off = 32; off; off >>= 1) fr += __shfl_xor(fr, off);
        if (lane == 0) fscratch[wv] = fr;
    }

    // x_raw: X at this lane's OWN output positions (unscaled; scale after sexp known)
    float x_out[16];
#pragma unroll
    for (int g = 0; g < 4; ++g) {
        unsigned off = swzoff(c_out, (rbase + g * 8) * 2);
        uint2 xh = *(const uint2*)((const char*)Bh + off);
        uint2 xl = *(const uint2*)((const char*)Bl + off);
        x_out[g * 4 + 0] = bf2f((unsigned short)(xh.x & 0xFFFF)) + bf2f((unsigned short)(xl.x & 0xFFFF));
        x_out[g * 4 + 1] = bf2f((unsigned short)(xh.x >> 16))    + bf2f((unsigned short)(xl.x >> 16));
        x_out[g * 4 + 2] = bf2f((unsigned short)(xh.y & 0xFFFF)) + bf2f((unsigned short)(xl.y & 0xFFFF));
        x_out[g * 4 + 3] = bf2f((unsigned short)(xh.y >> 16))    + bf2f((unsigned short)(xl.y >> 16));
    }
    __syncthreads();   // S2: fscratch visible AND all X reads drained (B safe to overwrite)

    // ||A||_2 <= (sum (A^2)_ij^2)^(1/4); tolerate ||X|| <= 4 (deg-13 remainder ok)
    const float total = fscratch[0] + fscratch[1] + fscratch[2] + fscratch[3];
    const float bound = sqrtf(sqrtf(total));
    int sexp = 0;
    if (bound > 4.f) {
        sexp = (int)ceilf(log2f(bound)) - 2;
        if (sexp < 0) sexp = 0;
        if (sexp > 24) sexp = 24;
    }
    const float sc1 = exp2f(-(float)sexp);
    const float sc2 = sc1 * sc1;
#pragma unroll
    for (int r = 0; r < 16; ++r) x_out[r] *= sc1;

    // ---- Y = acc * 4^-s -> store in place (X dead) ----
    {
        float v[16];
#pragma unroll
        for (int r = 0; r < 16; ++r) v[r] = acc[r] * sc2;
        store_cT(Bh, Bl, v, c_out, rbase);
    }
    __syncthreads();   // S3: Y visible

    // ---- resident Y A-side fragments ----
    bf16x8 ya_h[4], ya_l[4];
#pragma unroll
    for (int f = 0; f < 4; ++f) {
        ya_h[f] = ldfrag(Bh, wr + l31, f, lh);
        ya_l[f] = ldfrag(Bl, wr + l31, f, lh);
    }
    __syncthreads();   // S4: Y reads drained

    // ---- P init = CF[12]*I + CF[13]*X -> store in place (Y LDS copy dead) ----
    {
        float v[16];
#pragma unroll
        for (int r = 0; r < 16; ++r)
            v[r] = fmaf(dsel[r], CF[12], CF[13] * x_out[r]);
        store_cT(Bh, Bl, v, c_out, rbase);
    }
    __syncthreads();   // S5: P visible

    // ---- Horner (degree-13, chunk-2), in place: P <- (cI*I + cX*X) + Y*P ----
#pragma unroll 1
    for (int j = 5; j >= 0; --j) {
        bf16x8 pbh[4], pbl[4];
#pragma unroll
        for (int f = 0; f < 4; ++f) {
            pbh[f] = ldfrag(Bh, wc + l31, f, lh);
            pbl[f] = ldfrag(Bl, wc + l31, f, lh);
        }
        __syncthreads();   // read-drain: all waves fetched P before overwrite
        f32x16 a2 = mm3(ya_h, ya_l, pbh, pbl);
        float w[16];
        const float cI = CF[2 * j], cX = CF[2 * j + 1];
#pragma unroll
        for (int r = 0; r < 16; ++r)
            w[r] = fmaf(dsel[r], cI, fmaf(cX, x_out[r], a2[r]));
        store_cT(Bh, Bl, w, c_out, rbase);
        __syncthreads();   // write-visible
    }

    // ---- squarings in place; final one streams to global ----
    if (sexp == 0) {
        // P (hi+lo) is the answer; own positions, no barrier needed.
#pragma unroll
        for (int g = 0; g < 4; ++g) {
            unsigned off = swzoff(c_out, (rbase + g * 8) * 2);
            uint2 ph = *(const uint2*)((const char*)Bh + off);
            uint2 pl = *(const uint2*)((const char*)Bl + off);
            out[base + (size_t)(rbase + g * 8 + 0) * NB + c_out] = bf2f((unsigned short)(ph.x & 0xFFFF)) + bf2f((unsigned short)(pl.x & 0xFFFF));
            out[base + (size_t)(rbase + g * 8 + 1) * NB + c_out] = bf2f((unsigned short)(ph.x >> 16))    + bf2f((unsigned short)(pl.x >> 16));
            out[base + (size_t)(rbase + g * 8 + 2) * NB + c_out] = bf2f((unsigned short)(ph.y & 0xFFFF)) + bf2f((unsigned short)(pl.y & 0xFFFF));
            out[base + (size_t)(rbase + g * 8 + 3) * NB + c_out] = bf2f((unsigned short)(ph.y >> 16))    + bf2f((unsigned short)(pl.y >> 16));
        }
    } else {
#pragma unroll 1
        for (int t = 0; t < sexp; ++t) {
            bf16x8 pah[4], pal[4], pbh[4], pbl[4];
#pragma unroll
            for (int f = 0; f < 4; ++f) {
                pah[f] = ldfrag(Bh, wr + l31, f, lh);
                pal[f] = ldfrag(Bl, wr + l31, f, lh);
            }
            if (diag) {
#pragma unroll
                for (int f = 0; f < 4; ++f) { pbh[f] = pah[f]; pbl[f] = pal[f]; }
            } else {
#pragma unroll
                for (int f = 0; f < 4; ++f) {
                    pbh[f] = ldfrag(Bh, wc + l31, f, lh);
                    pbl[f] = ldfrag(Bl, wc + l31, f, lh);
                }
            }
            if (t == sexp - 1) {
                // final: no LDS rewrite -> no barriers; fp32 straight to global
                f32x16 a2 = mm3(pah, pal, pbh, pbl);
#pragma unroll
                for (int g = 0; g < 4; ++g)
#pragma unroll
                    for (int q = 0; q < 4; ++q)
                        out[base + (size_t)(rbase + g * 8 + q) * NB + c_out] = a2[g * 4 + q];
            } else {
                __syncthreads();   // read-drain
                f32x16 a2 = mm3(pah, pal, pbh, pbl);
                store_cT(Bh, Bl, (const float*)&a2, c_out, rbase);
                __syncthreads();   // write-visible
            }
        }
    }
}

extern "C" void kernel_launch(void* const* d_in, const int* in_sizes, int n_in,
                              void* d_out, int out_size, void* d_ws, size_t ws_size,
                              hipStream_t stream) {
    const float* in = reinterpret_cast<const float*>(d_in[0]);
    float* out = reinterpret_cast<float*>(d_out);
    const int nmat = in_sizes[0] / (NB * NB);
    hipLaunchKernelGGL(spd_expmap_mfma, dim3(nmat), dim3(TPB), 0, stream, in, out);
}

// Round 12
// 315.995 us; speedup vs baseline: 1.0177x; 1.0177x over previous
//
#include <hip/hip_runtime.h>
#include <math.h>

#define NB 64
#define TPB 128   // 2 waves/block, ONE MATRIX PER WAVE, zero barriers

// 1/k! for k = 0..13 (degree-13 Taylor)
__device__ __constant__ float CF[16] = {
    1.0f,
    1.0f,
    0.5f,
    1.6666666666666666e-01f,
    4.1666666666666664e-02f,
    8.3333333333333332e-03f,
    1.3888888888888889e-03f,
    1.9841269841269841e-04f,
    2.4801587301587302e-05f,
    2.7557319223985893e-06f,
    2.7557319223985888e-07f,
    2.5052108385441720e-08f,
    2.0876756987868100e-09f,
    1.6059043836821613e-10f,
    1.1470745597729725e-11f,
    7.6471637318198164e-13f
};

typedef __attribute__((ext_vector_type(8))) short bf16x8;
typedef __attribute__((ext_vector_type(16))) float f32x16;
typedef __attribute__((ext_vector_type(4))) unsigned int u32x4;

#define MFMA32 __builtin_amdgcn_mfma_f32_32x32x16_bf16

// packed split: (x0,x1) -> hi word (bf16(x0)|bf16(x1)<<16), lo word (residuals)
__device__ __forceinline__ void split_pk(float x0, float x1, unsigned& ph, unsigned& pl) {
    unsigned h;
    asm("v_cvt_pk_bf16_f32 %0, %1, %2" : "=v"(h) : "v"(x0), "v"(x1));
    float h0 = __builtin_bit_cast(float, h << 16);
    float h1 = __builtin_bit_cast(float, h & 0xFFFF0000u);
    float r0 = x0 - h0;
    float r1 = x1 - h1;
    unsigned l;
    asm("v_cvt_pk_bf16_f32 %0, %1, %2" : "=v"(l) : "v"(r0), "v"(r1));
    ph = h; pl = l;
}

__device__ __forceinline__ float bf2f(unsigned short h) {
    unsigned u = ((unsigned)h) << 16;
    return __builtin_bit_cast(float, u);
}

// byte offset of (row, byteInRow) in a swizzled 64x64 bf16 LDS matrix (128 B rows)
__device__ __forceinline__ unsigned swzoff(int row, int byteInRow) {
    return (unsigned)(row * 128 + (byteInRow ^ ((row & 7) << 4)));
}

// A/B fragment for v_mfma_f32_32x32x16_bf16, k-step f (k in [16f,16f+16)).
// lane: row = rowbase + (lane&31), k = 16f + 8*(lane>>5) + 0..7  -> 16B read.
__device__ __forceinline__ bf16x8 ldfrag(const unsigned short* buf, int row, int f, int lh) {
    const char* p = (const char*)buf + swzoff(row, f * 32 + lh * 16);
    return __builtin_bit_cast(bf16x8, *(const u32x4*)p);
}

// acc = Ahi*Bhi + Alo*Bhi + Ahi*Blo  over K=64 (4 k-steps each)
__device__ __forceinline__ f32x16 mm3(const bf16x8* ah, const bf16x8* al,
                                      const bf16x8* bh, const bf16x8* bl) {
    f32x16 acc = {};
#pragma unroll
    for (int f = 0; f < 4; ++f) acc = MFMA32(ah[f], bh[f], acc, 0, 0, 0);
#pragma unroll
    for (int f = 0; f < 4; ++f) acc = MFMA32(al[f], bh[f], acc, 0, 0, 0);
#pragma unroll
    for (int f = 0; f < 4; ++f) acc = MFMA32(ah[f], bl[f], acc, 0, 0, 0);
    return acc;
}

// Split v[16] into hi/lo bf16 and write TRANSPOSED into this wave's private
// buffer: value (row r, col c) -> LDS[c][r]; one ds_write_b64 per 4-row group.
__device__ __forceinline__ void store_cT(unsigned short* Bh, unsigned short* Bl,
                                         const float* v, int c_out, int rbase) {
#pragma unroll
    for (int g = 0; g < 4; ++g) {
        uint2 wh, wl;
        split_pk(v[g * 4 + 0], v[g * 4 + 1], wh.x, wl.x);
        split_pk(v[g * 4 + 2], v[g * 4 + 3], wh.y, wl.y);
        unsigned off = swzoff(c_out, (rbase + g * 8) * 2);
        *(uint2*)((char*)Bh + off) = wh;
        *(uint2*)((char*)Bl + off) = wl;
    }
}

// read hi+lo at this lane's own output positions for tile (c_out, rbase)
__device__ __forceinline__ void read_own(const unsigned short* Bh, const unsigned short* Bl,
                                         int c_out, int rbase, float* xv) {
#pragma unroll
    for (int g = 0; g < 4; ++g) {
        unsigned off = swzoff(c_out, (rbase + g * 8) * 2);
        uint2 xh = *(const uint2*)((const char*)Bh + off);
        uint2 xl = *(const uint2*)((const char*)Bl + off);
        xv[g * 4 + 0] = bf2f((unsigned short)(xh.x & 0xFFFF)) + bf2f((unsigned short)(xl.x & 0xFFFF));
        xv[g * 4 + 1] = bf2f((unsigned short)(xh.x >> 16))    + bf2f((unsigned short)(xl.x >> 16));
        xv[g * 4 + 2] = bf2f((unsigned short)(xh.y & 0xFFFF)) + bf2f((unsigned short)(xl.y & 0xFFFF));
        xv[g * 4 + 3] = bf2f((unsigned short)(xh.y >> 16))    + bf2f((unsigned short)(xl.y >> 16));
    }
}

// launch_bounds(128,2): min 2 waves/EU -> VGPR cap 256 (no spills expected ~230).
__global__ __launch_bounds__(TPB, 2)
void spd_expmap_mfma(const float* __restrict__ in, float* __restrict__ out)
{
    // Per-wave PRIVATE 16 KiB (hi 8KB + lo 8KB). No __syncthreads anywhere:
    // intra-wave LDS RAW is ordered by hardware lgkmcnt.
    __shared__ __align__(16) unsigned short SB[2 * 8192];
    const int tid  = threadIdx.x;
    const int lane = tid & 63;
    const int wv   = tid >> 6;
    unsigned short* Bh = SB + wv * 8192;
    unsigned short* Bl = Bh + 4096;

    const int l31  = lane & 31;
    const int lh   = lane >> 5;
    const size_t base = ((size_t)blockIdx.x * 2 + wv) * (NB * NB);

    // diagonal mask for this lane's 16 positions within a diag tile (rb==cb)
    unsigned dmask = 0;
#pragma unroll
    for (int g = 0; g < 4; ++g)
#pragma unroll
        for (int q = 0; q < 4; ++q)
            if (4 * lh + g * 8 + q == l31) dmask |= 1u << (g * 4 + q);

    // ---- stage: lane loads ROW lane of its matrix, split hi/lo, store swizzled ----
    {
        const float4* gp = (const float4*)(in + base + (size_t)lane * NB);
#pragma unroll
        for (int c = 0; c < 4; ++c) {       // 16 floats per chunk
            float4 t0 = gp[c * 4 + 0], t1 = gp[c * 4 + 1];
            float4 t2 = gp[c * 4 + 2], t3 = gp[c * 4 + 3];
            float vv[16] = {t0.x, t0.y, t0.z, t0.w, t1.x, t1.y, t1.z, t1.w,
                            t2.x, t2.y, t2.z, t2.w, t3.x, t3.y, t3.z, t3.w};
            unsigned hw[8], lw[8];
#pragma unroll
            for (int i = 0; i < 8; ++i)
                split_pk(vv[2 * i], vv[2 * i + 1], hw[i], lw[i]);
            u32x4 H0 = {hw[0], hw[1], hw[2], hw[3]}, H1 = {hw[4], hw[5], hw[6], hw[7]};
            u32x4 L0 = {lw[0], lw[1], lw[2], lw[3]}, L1 = {lw[4], lw[5], lw[6], lw[7]};
            unsigned o0 = swzoff(lane, c * 32), o1 = swzoff(lane, c * 32 + 16);
            *(u32x4*)((char*)Bh + o0) = H0; *(u32x4*)((char*)Bh + o1) = H1;
            *(u32x4*)((char*)Bl + o0) = L0; *(u32x4*)((char*)Bl + o1) = L1;
        }
    }

    // ---- mm1: all 4 tiles of A*A + Frobenius (wave-local) ----
    bf16x8 fh0[4], fl0[4], fh1[4], fl1[4];
#pragma unroll
    for (int f = 0; f < 4; ++f) {
        fh0[f] = ldfrag(Bh, l31, f, lh);
        fl0[f] = ldfrag(Bl, l31, f, lh);
        fh1[f] = ldfrag(Bh, 32 + l31, f, lh);
        fl1[f] = ldfrag(Bl, 32 + l31, f, lh);
    }
    f32x16 a00 = mm3(fh0, fl0, fh0, fl0);
    f32x16 a01 = mm3(fh0, fl0, fh1, fl1);
    f32x16 a10 = mm3(fh1, fl1, fh0, fl0);
    f32x16 a11 = mm3(fh1, fl1, fh1, fl1);

    float fr = 0.f;
#pragma unroll
    for (int r = 0; r < 16; ++r)
        fr += a00[r] * a00[r] + a01[r] * a01[r] + a10[r] * a10[r] + a11[r] * a11[r];
#pragma unroll
    for (int off = 32; off; off >>= 1) fr += __shfl_xor(fr, off);

    // ||A||_2 <= (sum (A^2)_ij^2)^(1/4); tolerate ||X|| <= 4 (deg-13 remainder ok)
    const float bound = sqrtf(sqrtf(fr));
    int sexp = 0;
    if (bound > 4.f) {
        sexp = (int)ceilf(log2f(bound)) - 2;
        if (sexp < 0) sexp = 0;
        if (sexp > 24) sexp = 24;
    }
    const float sc1 = exp2f(-(float)sexp);
    const float sc2 = sc1 * sc1;

    // ---- x at own positions per tile (X still live in LDS), scaled ----
    float x00[16], x01[16], x10[16], x11[16];
    read_own(Bh, Bl, l31,      4 * lh,      x00);
    read_own(Bh, Bl, 32 + l31, 4 * lh,      x01);
    read_own(Bh, Bl, l31,      32 + 4 * lh, x10);
    read_own(Bh, Bl, 32 + l31, 32 + 4 * lh, x11);
#pragma unroll
    for (int r = 0; r < 16; ++r) {
        x00[r] *= sc1; x01[r] *= sc1; x10[r] *= sc1; x11[r] *= sc1;
    }

    // ---- Y = (A*A)*4^-s -> store in place (X dead) ----
    {
        float w[16];
#pragma unroll
        for (int r = 0; r < 16; ++r) w[r] = a00[r] * sc2;
        store_cT(Bh, Bl, w, l31, 4 * lh);
#pragma unroll
        for (int r = 0; r < 16; ++r) w[r] = a01[r] * sc2;
        store_cT(Bh, Bl, w, 32 + l31, 4 * lh);
#pragma unroll
        for (int r = 0; r < 16; ++r) w[r] = a10[r] * sc2;
        store_cT(Bh, Bl, w, l31, 32 + 4 * lh);
#pragma unroll
        for (int r = 0; r < 16; ++r) w[r] = a11[r] * sc2;
        store_cT(Bh, Bl, w, 32 + l31, 32 + 4 * lh);
    }

    // ---- resident Y A-side fragments ----
    bf16x8 yh0[4], yl0[4], yh1[4], yl1[4];
#pragma unroll
    for (int f = 0; f < 4; ++f) {
        yh0[f] = ldfrag(Bh, l31, f, lh);
        yl0[f] = ldfrag(Bl, l31, f, lh);
        yh1[f] = ldfrag(Bh, 32 + l31, f, lh);
        yl1[f] = ldfrag(Bl, 32 + l31, f, lh);
    }

    // ---- P init = CF[12]*I + CF[13]*X -> in place (Y LDS copy consumed into regs) ----
    {
        float w[16];
#pragma unroll
        for (int r = 0; r < 16; ++r)
            w[r] = CF[13] * x00[r] + (((dmask >> r) & 1) ? CF[12] : 0.f);
        store_cT(Bh, Bl, w, l31, 4 * lh);
#pragma unroll
        for (int r = 0; r < 16; ++r) w[r] = CF[13] * x01[r];
        store_cT(Bh, Bl, w, 32 + l31, 4 * lh);
#pragma unroll
        for (int r = 0; r < 16; ++r) w[r] = CF[13] * x10[r];
        store_cT(Bh, Bl, w, l31, 32 + 4 * lh);
#pragma unroll
        for (int r = 0; r < 16; ++r)
            w[r] = CF[13] * x11[r] + (((dmask >> r) & 1) ? CF[12] : 0.f);
        store_cT(Bh, Bl, w, 32 + l31, 32 + 4 * lh);
    }

    // ---- Horner (deg-13):  P <- (cI*I + cX*X) + Y*P ----
#pragma unroll 1
    for (int j = 5; j >= 0; --j) {
        const float cI = CF[2 * j], cX = CF[2 * j + 1];
        bf16x8 ph0[4], pl0[4], ph1[4], pl1[4];
#pragma unroll
        for (int f = 0; f < 4; ++f) {          // read ALL frags before any write
            ph0[f] = ldfrag(Bh, l31, f, lh);
            pl0[f] = ldfrag(Bl, l31, f, lh);
            ph1[f] = ldfrag(Bh, 32 + l31, f, lh);
            pl1[f] = ldfrag(Bl, 32 + l31, f, lh);
        }
        float w[16];
        {
            f32x16 t = mm3(yh0, yl0, ph0, pl0);
#pragma unroll
            for (int r = 0; r < 16; ++r)
                w[r] = fmaf(cX, x00[r], t[r]) + (((dmask >> r) & 1) ? cI : 0.f);
            store_cT(Bh, Bl, w, l31, 4 * lh);
        }
        {
            f32x16 t = mm3(yh0, yl0, ph1, pl1);
#pragma unroll
            for (int r = 0; r < 16; ++r) w[r] = fmaf(cX, x01[r], t[r]);
            store_cT(Bh, Bl, w, 32 + l31, 4 * lh);
        }
        {
            f32x16 t = mm3(yh1, yl1, ph0, pl0);
#pragma unroll
            for (int r = 0; r < 16; ++r) w[r] = fmaf(cX, x10[r], t[r]);
            store_cT(Bh, Bl, w, l31, 32 + 4 * lh);
        }
        {
            f32x16 t = mm3(yh1, yl1, ph1, pl1);
#pragma unroll
            for (int r = 0; r < 16; ++r)
                w[r] = fmaf(cX, x11[r], t[r]) + (((dmask >> r) & 1) ? cI : 0.f);
            store_cT(Bh, Bl, w, 32 + l31, 32 + 4 * lh);
        }
    }

    // ---- squarings (wave-uniform count); final streams to global ----
    if (sexp == 0) {
        float w[16];
        read_own(Bh, Bl, l31, 4 * lh, w);
#pragma unroll
        for (int g = 0; g < 4; ++g)
#pragma unroll
            for (int q = 0; q < 4; ++q)
                out[base + (size_t)(4 * lh + g * 8 + q) * NB + l31] = w[g * 4 + q];
        read_own(Bh, Bl, 32 + l31, 4 * lh, w);
#pragma unroll
        for (int g = 0; g < 4; ++g)
#pragma unroll
            for (int q = 0; q < 4; ++q)
                out[base + (size_t)(4 * lh + g * 8 + q) * NB + 32 + l31] = w[g * 4 + q];
        read_own(Bh, Bl, l31, 32 + 4 * lh, w);
#pragma unroll
        for (int g = 0; g < 4; ++g)
#pragma unroll
            for (int q = 0; q < 4; ++q)
                out[base + (size_t)(32 + 4 * lh + g * 8 + q) * NB + l31] = w[g * 4 + q];
        read_own(Bh, Bl, 32 + l31, 32 + 4 * lh, w);
#pragma unroll
        for (int g = 0; g < 4; ++g)
#pragma unroll
            for (int q = 0; q < 4; ++q)
                out[base + (size_t)(32 + 4 * lh + g * 8 + q) * NB + 32 + l31] = w[g * 4 + q];
    } else {
#pragma unroll 1
        for (int t = 0; t < sexp; ++t) {
            bf16x8 ph0[4], pl0[4], ph1[4], pl1[4];
#pragma unroll
            for (int f = 0; f < 4; ++f) {
                ph0[f] = ldfrag(Bh, l31, f, lh);
                pl0[f] = ldfrag(Bl, l31, f, lh);
                ph1[f] = ldfrag(Bh, 32 + l31, f, lh);
                pl1[f] = ldfrag(Bl, 32 + l31, f, lh);
            }
            f32x16 s00 = mm3(ph0, pl0, ph0, pl0);
            f32x16 s01 = mm3(ph0, pl0, ph1, pl1);
            f32x16 s10 = mm3(ph1, pl1, ph0, pl0);
            f32x16 s11 = mm3(ph1, pl1, ph1, pl1);
            if (t == sexp - 1) {
#pragma unroll
                for (int g = 0; g < 4; ++g)
#pragma unroll
                    for (int q = 0; q < 4; ++q) {
                        out[base + (size_t)(4 * lh + g * 8 + q) * NB + l31]           = s00[g * 4 + q];
                        out[base + (size_t)(4 * lh + g * 8 + q) * NB + 32 + l31]      = s01[g * 4 + q];
                        out[base + (size_t)(32 + 4 * lh + g * 8 + q) * NB + l31]      = s10[g * 4 + q];
                        out[base + (size_t)(32 + 4 * lh + g * 8 + q) * NB + 32 + l31] = s11[g * 4 + q];
                    }
            } else {
                store_cT(Bh, Bl, (const float*)&s00, l31, 4 * lh);
                store_cT(Bh, Bl, (const float*)&s01, 32 + l31, 4 * lh);
                store_cT(Bh, Bl, (const float*)&s10, l31, 32 + 4 * lh);
                store_cT(Bh, Bl, (const float*)&s11, 32 + l31, 32 + 4 * lh);
            }
        }
    }
}

extern "C" void kernel_launch(void* const* d_in, const int* in_sizes, int n_in,
                              void* d_out, int out_size, void* d_ws, size_t ws_size,
                              hipStream_t stream) {
    const float* in = reinterpret_cast<const float*>(d_in[0]);
    float* out = reinterpret_cast<float*>(d_out);
    const int nmat = in_sizes[0] / (NB * NB);
    hipLaunchKernelGGL(spd_expmap_mfma, dim3(nmat / 2), dim3(TPB), 0, stream, in, out);
}

// Round 13
// 264.906 us; speedup vs baseline: 1.2140x; 1.1929x over previous
//
#include <hip/hip_runtime.h>
#include <math.h>

#define NB 64
#define TPB 64   // ONE WAVE PER MATRIX; no LDS, no barriers, all-register

// 1/k! for k = 0..13 (degree-13 Taylor)
__device__ __constant__ float CF[16] = {
    1.0f,
    1.0f,
    0.5f,
    1.6666666666666666e-01f,
    4.1666666666666664e-02f,
    8.3333333333333332e-03f,
    1.3888888888888889e-03f,
    1.9841269841269841e-04f,
    2.4801587301587302e-05f,
    2.7557319223985893e-06f,
    2.7557319223985888e-07f,
    2.5052108385441720e-08f,
    2.0876756987868100e-09f,
    1.6059043836821613e-10f,
    1.1470745597729725e-11f,
    7.6471637318198164e-13f
};

typedef __attribute__((ext_vector_type(8))) short bf16x8;
typedef __attribute__((ext_vector_type(16))) float f32x16;
typedef __attribute__((ext_vector_type(4))) unsigned int u32x4;

#define MFMA32 __builtin_amdgcn_mfma_f32_32x32x16_bf16
#define BCH(x) __builtin_bit_cast(bf16x8, x)

__device__ __forceinline__ float bf2f(unsigned short h) {
    unsigned u = ((unsigned)h) << 16;
    return __builtin_bit_cast(float, u);
}

// packed split: (x0,x1) -> hi word (bf16(x0)|bf16(x1)<<16), lo word (residuals)
__device__ __forceinline__ void split_pk(float x0, float x1, unsigned& ph, unsigned& pl) {
    unsigned h;
    asm("v_cvt_pk_bf16_f32 %0, %1, %2" : "=v"(h) : "v"(x0), "v"(x1));
    float h0 = __builtin_bit_cast(float, h << 16);
    float h1 = __builtin_bit_cast(float, h & 0xFFFF0000u);
    float r0 = x0 - h0;
    float r1 = x1 - h1;
    unsigned l;
    asm("v_cvt_pk_bf16_f32 %0, %1, %2" : "=v"(l) : "v"(r0), "v"(r1));
    ph = h; pl = l;
}

// exchange halves: after call, a = [a.lanes0-31 | b.lanes0-31], b = [a.lanes32-63 | b.lanes32-63]
__device__ __forceinline__ void pswap(unsigned& a, unsigned& b, int lh) {
#if __has_builtin(__builtin_amdgcn_permlane32_swap)
    auto r = __builtin_amdgcn_permlane32_swap((int)a, (int)b, false, false);
    a = (unsigned)r[0];
    b = (unsigned)r[1];
#else
    unsigned pa = (unsigned)__shfl_xor((int)a, 32);
    unsigned pb = (unsigned)__shfl_xor((int)b, 32);
    unsigned o0 = lh ? pb : a;
    unsigned o1 = lh ? b : pa;
    a = o0; b = o1;
#endif
}

// acc-layout tile values v[16] (= C[rb+4lh+8g+q][cb+l31]) -> 2 operand frags
// (hi+lo) for operand rowblock cb, k-range [rb, rb+32), via symmetry of C.
// frag word order: [firstHalf q01, firstHalf q23, secondHalf q01, secondHalf q23].
__device__ __forceinline__ void tile_to_op(const float* v, int lh, u32x4* fh, u32x4* fl) {
    unsigned Wh[4][2], Wl[4][2];
#pragma unroll
    for (int g = 0; g < 4; ++g) {
        split_pk(v[g * 4 + 0], v[g * 4 + 1], Wh[g][0], Wl[g][0]);
        split_pk(v[g * 4 + 2], v[g * 4 + 3], Wh[g][1], Wl[g][1]);
    }
#pragma unroll
    for (int p = 0; p < 2; ++p) {
        unsigned a0 = Wh[2 * p][0], b0 = Wh[2 * p + 1][0];
        unsigned a1 = Wh[2 * p][1], b1 = Wh[2 * p + 1][1];
        pswap(a0, b0, lh);
        pswap(a1, b1, lh);
        fh[p] = (u32x4){a0, a1, b0, b1};
        a0 = Wl[2 * p][0]; b0 = Wl[2 * p + 1][0];
        a1 = Wl[2 * p][1]; b1 = Wl[2 * p + 1][1];
        pswap(a0, b0, lh);
        pswap(a1, b1, lh);
        fl[p] = (u32x4){a0, a1, b0, b1};
    }
}

// acc = Ahi*Bhi + Alo*Bhi + Ahi*Blo over K=64 (operands as u32x4[4] frag arrays)
__device__ __forceinline__ f32x16 mm3v(const u32x4* ah, const u32x4* al,
                                       const u32x4* bh, const u32x4* bl) {
    f32x16 acc = {};
#pragma unroll
    for (int f = 0; f < 4; ++f) acc = MFMA32(BCH(ah[f]), BCH(bh[f]), acc, 0, 0, 0);
#pragma unroll
    for (int f = 0; f < 4; ++f) acc = MFMA32(BCH(al[f]), BCH(bh[f]), acc, 0, 0, 0);
#pragma unroll
    for (int f = 0; f < 4; ++f) acc = MFMA32(BCH(ah[f]), BCH(bl[f]), acc, 0, 0, 0);
    return acc;
}

// write acc tile (R,C) to global via symmetry: row C*32+l31, cols R*32+4lh+8g+q -> float4 rows
__device__ __forceinline__ void wr_tile(float* __restrict__ out, size_t base,
                                        int C, int R, int l31, int lh, const float* w) {
    float* rowp = out + base + (size_t)(C * 32 + l31) * NB + R * 32 + 4 * lh;
#pragma unroll
    for (int g = 0; g < 4; ++g) {
        float4 v = make_float4(w[g * 4 + 0], w[g * 4 + 1], w[g * 4 + 2], w[g * 4 + 3]);
        *reinterpret_cast<float4*>(rowp + 8 * g) = v;
    }
}

__global__ __launch_bounds__(TPB, 2)
void spd_expmap_reg(const float* __restrict__ in, float* __restrict__ out)
{
    const int lane = threadIdx.x & 63;
    const int l31 = lane & 31;
    const int lh  = lane >> 5;
    const size_t base = (size_t)blockIdx.x * (NB * NB);
    const float* rp0 = in + base + (size_t)l31 * NB;        // row l31
    const float* rp1 = rp0 + (size_t)32 * NB;               // row 32+l31

    unsigned dmask = 0;
#pragma unroll
    for (int g = 0; g < 4; ++g)
#pragma unroll
        for (int q = 0; q < 4; ++q)
            if (4 * lh + 8 * g + q == l31) dmask |= 1u << (g * 4 + q);

    // ---- X operand frags straight from global: rows R*32+l31, cols 16f+8lh..+8 ----
    u32x4 XH[2][4], XL[2][4];
#pragma unroll
    for (int R = 0; R < 2; ++R) {
        const float* rp = R ? rp1 : rp0;
#pragma unroll
        for (int f = 0; f < 4; ++f) {
            const float* q = rp + 16 * f + 8 * lh;
            float4 a = *reinterpret_cast<const float4*>(q);
            float4 b = *reinterpret_cast<const float4*>(q + 4);
            unsigned h0, l0, h1, l1, h2, l2, h3, l3;
            split_pk(a.x, a.y, h0, l0);
            split_pk(a.z, a.w, h1, l1);
            split_pk(b.x, b.y, h2, l2);
            split_pk(b.z, b.w, h3, l3);
            XH[R][f] = (u32x4){h0, h1, h2, h3};
            XL[R][f] = (u32x4){l0, l1, l2, l3};
        }
    }

    // ---- x tiles at acc positions via symmetry: x[R][C] from row C*32+l31, col R*32+4lh+8g ----
    float x00[16], x10[16], x01[16], x11[16];
#pragma unroll
    for (int g = 0; g < 4; ++g) {
        float4 t;
        t = *reinterpret_cast<const float4*>(rp0 + 4 * lh + 8 * g);
        x00[g*4+0] = t.x; x00[g*4+1] = t.y; x00[g*4+2] = t.z; x00[g*4+3] = t.w;
        t = *reinterpret_cast<const float4*>(rp0 + 32 + 4 * lh + 8 * g);
        x10[g*4+0] = t.x; x10[g*4+1] = t.y; x10[g*4+2] = t.z; x10[g*4+3] = t.w;
        t = *reinterpret_cast<const float4*>(rp1 + 4 * lh + 8 * g);
        x01[g*4+0] = t.x; x01[g*4+1] = t.y; x01[g*4+2] = t.z; x01[g*4+3] = t.w;
        t = *reinterpret_cast<const float4*>(rp1 + 32 + 4 * lh + 8 * g);
        x11[g*4+0] = t.x; x11[g*4+1] = t.y; x11[g*4+2] = t.z; x11[g*4+3] = t.w;
    }

    // ---- mm1: acc tiles of A*A ----
    f32x16 a00 = mm3v(XH[0], XL[0], XH[0], XL[0]);
    f32x16 a01 = mm3v(XH[0], XL[0], XH[1], XL[1]);
    f32x16 a10 = mm3v(XH[1], XL[1], XH[0], XL[0]);
    f32x16 a11 = mm3v(XH[1], XL[1], XH[1], XL[1]);

    float fr = 0.f;
#pragma unroll
    for (int r = 0; r < 16; ++r)
        fr += a00[r]*a00[r] + a01[r]*a01[r] + a10[r]*a10[r] + a11[r]*a11[r];
#pragma unroll
    for (int off = 32; off; off >>= 1) fr += __shfl_xor(fr, off);

    // ||A||_2 <= (sum (A^2)_ij^2)^(1/4); tolerate ||X|| <= 4
    const float bound = sqrtf(sqrtf(fr));
    int sexp = 0;
    if (bound > 4.f) {
        sexp = (int)ceilf(log2f(bound)) - 2;
        if (sexp < 0) sexp = 0;
        if (sexp > 24) sexp = 24;
    }
    const float sc1 = exp2f(-(float)sexp);
    const float sc2 = sc1 * sc1;

#pragma unroll
    for (int r = 0; r < 16; ++r) { x00[r] *= sc1; x10[r] *= sc1; x01[r] *= sc1; x11[r] *= sc1; }

    // ---- Yop = operand form of (A*A)*4^-s ----
    u32x4 YH[2][4], YL[2][4];
    {
        float v[16];
#pragma unroll
        for (int r = 0; r < 16; ++r) v[r] = a00[r] * sc2;
        tile_to_op(v, lh, &YH[0][0], &YL[0][0]);
#pragma unroll
        for (int r = 0; r < 16; ++r) v[r] = a10[r] * sc2;
        tile_to_op(v, lh, &YH[0][2], &YL[0][2]);
#pragma unroll
        for (int r = 0; r < 16; ++r) v[r] = a01[r] * sc2;
        tile_to_op(v, lh, &YH[1][0], &YL[1][0]);
#pragma unroll
        for (int r = 0; r < 16; ++r) v[r] = a11[r] * sc2;
        tile_to_op(v, lh, &YH[1][2], &YL[1][2]);
    }

    // ---- Pop init = operand form of CF[12]*I + CF[13]*X ----
    u32x4 PH[2][4], PL[2][4];
    {
        float v[16];
#pragma unroll
        for (int r = 0; r < 16; ++r)
            v[r] = CF[13] * x00[r] + (((dmask >> r) & 1) ? CF[12] : 0.f);
        tile_to_op(v, lh, &PH[0][0], &PL[0][0]);
#pragma unroll
        for (int r = 0; r < 16; ++r) v[r] = CF[13] * x10[r];
        tile_to_op(v, lh, &PH[0][2], &PL[0][2]);
#pragma unroll
        for (int r = 0; r < 16; ++r) v[r] = CF[13] * x01[r];
        tile_to_op(v, lh, &PH[1][0], &PL[1][0]);
#pragma unroll
        for (int r = 0; r < 16; ++r)
            v[r] = CF[13] * x11[r] + (((dmask >> r) & 1) ? CF[12] : 0.f);
        tile_to_op(v, lh, &PH[1][2], &PL[1][2]);
    }

    // ---- Horner (deg-13): P <- (cI*I + cX*X) + Y*P ; phased by col-block for VGPR ----
#pragma unroll 1
    for (int j = 5; j >= 0; --j) {
        const float cI = CF[2 * j], cX = CF[2 * j + 1];
        const bool last = (j == 0) && (sexp == 0);
        {   // phase A: col-block 0 (uses PH[0] as B; rebuild PH[0] after)
            f32x16 t0 = mm3v(YH[0], YL[0], PH[0], PL[0]);
            f32x16 t1 = mm3v(YH[1], YL[1], PH[0], PL[0]);
            float w0[16], w1[16];
#pragma unroll
            for (int r = 0; r < 16; ++r) {
                w0[r] = fmaf(cX, x00[r], t0[r]) + (((dmask >> r) & 1) ? cI : 0.f);
                w1[r] = fmaf(cX, x10[r], t1[r]);
            }
            if (last) {
                wr_tile(out, base, 0, 0, l31, lh, w0);
                wr_tile(out, base, 0, 1, l31, lh, w1);
            } else {
                tile_to_op(w0, lh, &PH[0][0], &PL[0][0]);
                tile_to_op(w1, lh, &PH[0][2], &PL[0][2]);
            }
        }
        {   // phase B: col-block 1
            f32x16 t0 = mm3v(YH[0], YL[0], PH[1], PL[1]);
            f32x16 t1 = mm3v(YH[1], YL[1], PH[1], PL[1]);
            float w0[16], w1[16];
#pragma unroll
            for (int r = 0; r < 16; ++r) {
                w0[r] = fmaf(cX, x01[r], t0[r]);
                w1[r] = fmaf(cX, x11[r], t1[r]) + (((dmask >> r) & 1) ? cI : 0.f);
            }
            if (last) {
                wr_tile(out, base, 1, 0, l31, lh, w0);
                wr_tile(out, base, 1, 1, l31, lh, w1);
            } else {
                tile_to_op(w0, lh, &PH[1][0], &PL[1][0]);
                tile_to_op(w1, lh, &PH[1][2], &PL[1][2]);
            }
        }
    }

    // ---- squarings: P <- P*P ; final streams to global ----
#pragma unroll 1
    for (int t = 0; t < sexp; ++t) {
        f32x16 s00 = mm3v(PH[0], PL[0], PH[0], PL[0]);
        f32x16 s01 = mm3v(PH[0], PL[0], PH[1], PL[1]);
        f32x16 s10 = mm3v(PH[1], PL[1], PH[0], PL[0]);
        f32x16 s11 = mm3v(PH[1], PL[1], PH[1], PL[1]);
        float w[16];
        if (t == sexp - 1) {
#pragma unroll
            for (int r = 0; r < 16; ++r) w[r] = s00[r];
            wr_tile(out, base, 0, 0, l31, lh, w);
#pragma unroll
            for (int r = 0; r < 16; ++r) w[r] = s10[r];
            wr_tile(out, base, 0, 1, l31, lh, w);
#pragma unroll
            for (int r = 0; r < 16; ++r) w[r] = s01[r];
            wr_tile(out, base, 1, 0, l31, lh, w);
#pragma unroll
            for (int r = 0; r < 16; ++r) w[r] = s11[r];
            wr_tile(out, base, 1, 1, l31, lh, w);
        } else {
#pragma unroll
            for (int r = 0; r < 16; ++r) w[r] = s00[r];
            tile_to_op(w, lh, &PH[0][0], &PL[0][0]);
#pragma unroll
            for (int r = 0; r < 16; ++r) w[r] = s10[r];
            tile_to_op(w, lh, &PH[0][2], &PL[0][2]);
#pragma unroll
            for (int r = 0; r < 16; ++r) w[r] = s01[r];
            tile_to_op(w, lh, &PH[1][0], &PL[1][0]);
#pragma unroll
            for (int r = 0; r < 16; ++r) w[r] = s11[r];
            tile_to_op(w, lh, &PH[1][2], &PL[1][2]);
        }
    }
}

extern "C" void kernel_launch(void* const* d_in, const int* in_sizes, int n_in,
                              void* d_out, int out_size, void* d_ws, size_t ws_size,
                              hipStream_t stream) {
    const float* in = reinterpret_cast<const float*>(d_in[0]);
    float* out = reinterpret_cast<float*>(d_out);
    const int nmat = in_sizes[0] / (NB * NB);
    hipLaunchKernelGGL(spd_expmap_reg, dim3(nmat), dim3(TPB), 0, stream, in, out);
}